// Round 2
// baseline (15762.404 us; speedup 1.0000x reference)
//
#include <hip/hip_runtime.h>
#include <math.h>

#define N      8192
#define KDIM   64
#define EPS_F      0.05f
#define INV_EPS    20.0f
// eps * log(1/8192) ; log_mu == log_nu
#define EPS_LOG_MU (-0.45054566736396444f)
#define THRESH     0.001f
#define NEG_BIG    (-1e30f)
#define NCHUNK 64          // column chunks, 128 cols each

// ---------------- init ----------------
__global__ void init_kernel(float* u, float* v, int* done) {
    int t = blockIdx.x * blockDim.x + threadIdx.x;
    if (t < N) { u[t] = 0.0f; v[t] = 0.0f; }
    if (t == 0) *done = 0;
}

// ---------------- squared row norms ----------------
__global__ void norms_kernel(const float* __restrict__ S, const float* __restrict__ T,
                             float* __restrict__ sq_s, float* __restrict__ sq_t) {
    int t = blockIdx.x * blockDim.x + threadIdx.x;   // 0 .. 16383
    const float* p = (t < N) ? S : T;
    int r = t & (N - 1);
    const float4* row = reinterpret_cast<const float4*>(p + (size_t)r * KDIM);
    float acc = 0.0f;
#pragma unroll
    for (int q = 0; q < KDIM / 4; ++q) {
        float4 a = row[q];
        acc += a.x * a.x + a.y * a.y + a.z * a.z + a.w * a.w;
    }
    if (t < N) sq_s[r] = acc; else sq_t[r] = acc;
}

// ---------------- fused cost + LSE pass ----------------
// Computes, for each row i of RP: online-lse over cols j of
//   L_ij = (w_j - max(sq_r[i] + sq_c[j] - 2*dot(RP_i, CP_j), 0)) / eps
// Each block: 64-row tile x 128-col chunk (two 64-col LDS tiles).
// Writes per-chunk partial (m, s) to pm/ps [NCHUNK][N].
__global__ __launch_bounds__(256) void lse_pass(const float* __restrict__ RP,
                                                const float* __restrict__ CP,
                                                const float* __restrict__ sq_r,
                                                const float* __restrict__ sq_c,
                                                const float* __restrict__ w,
                                                float* __restrict__ pm,
                                                float* __restrict__ ps,
                                                const int* __restrict__ done) {
    if (*done) return;
    __shared__ float sA[64 * 64];   // [k][row]
    __shared__ float sB[64 * 64];   // [k][col]
    int rt = blockIdx.x & 127;      // row tile
    int ck = blockIdx.x >> 7;       // col chunk (128 cols)
    int t  = threadIdx.x;
    int tx = t & 15, ty = t >> 4;
    int r0 = ty * 4, c0 = tx * 4;

    {   // load + transpose row-points tile (once)
        int r  = t >> 2;
        int k0 = (t & 3) * 16;
        const float4* src = reinterpret_cast<const float4*>(RP + (size_t)(rt * 64 + r) * KDIM + k0);
        float4 a0 = src[0], a1 = src[1], a2 = src[2], a3 = src[3];
        float vals[16] = {a0.x,a0.y,a0.z,a0.w, a1.x,a1.y,a1.z,a1.w,
                          a2.x,a2.y,a2.z,a2.w, a3.x,a3.y,a3.z,a3.w};
#pragma unroll
        for (int q = 0; q < 16; ++q) sA[(k0 + q) * 64 + r] = vals[q];
    }

    float sqr[4];
#pragma unroll
    for (int i = 0; i < 4; ++i) sqr[i] = sq_r[rt * 64 + r0 + i];

    float m[4], s[4];
#pragma unroll
    for (int i = 0; i < 4; ++i) { m[i] = NEG_BIG; s[i] = 0.0f; }

    for (int jt = 0; jt < 2; ++jt) {
        int jbase = ck * 128 + jt * 64;
        __syncthreads();   // jt=0: after sA stores; jt=1: protect sB reuse
        {   // load + transpose col-points tile
            int r  = t >> 2;
            int k0 = (t & 3) * 16;
            const float4* src = reinterpret_cast<const float4*>(CP + (size_t)(jbase + r) * KDIM + k0);
            float4 a0 = src[0], a1 = src[1], a2 = src[2], a3 = src[3];
            float vals[16] = {a0.x,a0.y,a0.z,a0.w, a1.x,a1.y,a1.z,a1.w,
                              a2.x,a2.y,a2.z,a2.w, a3.x,a3.y,a3.z,a3.w};
#pragma unroll
            for (int q = 0; q < 16; ++q) sB[(k0 + q) * 64 + r] = vals[q];
        }
        __syncthreads();

        float acc[4][4];
#pragma unroll
        for (int i = 0; i < 4; ++i)
#pragma unroll
            for (int j = 0; j < 4; ++j) acc[i][j] = 0.0f;

#pragma unroll 8
        for (int k = 0; k < 64; ++k) {
            float4 a4 = *reinterpret_cast<const float4*>(&sA[k * 64 + r0]);
            float4 b4 = *reinterpret_cast<const float4*>(&sB[k * 64 + c0]);
            float ar[4] = {a4.x, a4.y, a4.z, a4.w};
            float br[4] = {b4.x, b4.y, b4.z, b4.w};
#pragma unroll
            for (int i = 0; i < 4; ++i)
#pragma unroll
                for (int j = 0; j < 4; ++j)
                    acc[i][j] = fmaf(ar[i], br[j], acc[i][j]);
        }

        float4 w4  = *reinterpret_cast<const float4*>(w + jbase + c0);
        float4 sc4 = *reinterpret_cast<const float4*>(sq_c + jbase + c0);
        float wj[4]  = {w4.x, w4.y, w4.z, w4.w};
        float sqc[4] = {sc4.x, sc4.y, sc4.z, sc4.w};
#pragma unroll
        for (int i = 0; i < 4; ++i) {
            float L0 = (wj[0] - fmaxf(sqr[i] + sqc[0] - 2.0f * acc[i][0], 0.0f)) * INV_EPS;
            float L1 = (wj[1] - fmaxf(sqr[i] + sqc[1] - 2.0f * acc[i][1], 0.0f)) * INV_EPS;
            float L2 = (wj[2] - fmaxf(sqr[i] + sqc[2] - 2.0f * acc[i][2], 0.0f)) * INV_EPS;
            float L3 = (wj[3] - fmaxf(sqr[i] + sqc[3] - 2.0f * acc[i][3], 0.0f)) * INV_EPS;
            float mx = fmaxf(fmaxf(L0, L1), fmaxf(L2, L3));
            float mn = fmaxf(m[i], mx);
            s[i] = s[i] * __expf(m[i] - mn) + __expf(L0 - mn) + __expf(L1 - mn)
                                            + __expf(L2 - mn) + __expf(L3 - mn);
            m[i] = mn;
        }
    }

    // reduce across the 16 lanes (tx) sharing the same rows
#pragma unroll
    for (int off = 1; off < 16; off <<= 1) {
#pragma unroll
        for (int i = 0; i < 4; ++i) {
            float mo = __shfl_xor(m[i], off);
            float so = __shfl_xor(s[i], off);
            float mn = fmaxf(m[i], mo);
            s[i] = s[i] * __expf(m[i] - mn) + so * __expf(mo - mn);
            m[i] = mn;
        }
    }
    if (tx == 0) {
#pragma unroll
        for (int i = 0; i < 4; ++i) {
            size_t idx = (size_t)ck * N + rt * 64 + r0 + i;
            pm[idx] = m[i];
            ps[idx] = s[i];
        }
    }
}

// ---------------- u update (with convergence diff) ----------------
__global__ __launch_bounds__(256) void u_reduce(const float* __restrict__ pm,
                                                const float* __restrict__ ps,
                                                float* __restrict__ u,
                                                float* __restrict__ blockDiff,
                                                const int* __restrict__ done) {
    if (*done) return;
    int i = blockIdx.x * 256 + threadIdx.x;
    float m = NEG_BIG, s = 0.0f;
#pragma unroll 4
    for (int c = 0; c < NCHUNK; ++c) {
        float mc = pm[(size_t)c * N + i];
        float sc = ps[(size_t)c * N + i];
        float mn = fmaxf(m, mc);
        s = s * __expf(m - mn) + sc * __expf(mc - mn);
        m = mn;
    }
    float unew = EPS_LOG_MU - EPS_F * (m + __logf(s));
    float d = fabsf(unew - u[i]);
    u[i] = unew;
#pragma unroll
    for (int off = 32; off; off >>= 1) d += __shfl_xor(d, off);
    __shared__ float wsum[4];
    int lane = threadIdx.x & 63, wave = threadIdx.x >> 6;
    if (lane == 0) wsum[wave] = d;
    __syncthreads();
    if (threadIdx.x == 0)
        blockDiff[blockIdx.x] = wsum[0] + wsum[1] + wsum[2] + wsum[3];
}

// ---------------- v update ----------------
__global__ __launch_bounds__(256) void v_reduce(const float* __restrict__ pm,
                                                const float* __restrict__ ps,
                                                float* __restrict__ v,
                                                const int* __restrict__ done) {
    if (*done) return;
    int j = blockIdx.x * 256 + threadIdx.x;
    float m = NEG_BIG, s = 0.0f;
#pragma unroll 4
    for (int c = 0; c < NCHUNK; ++c) {
        float mc = pm[(size_t)c * N + j];
        float sc = ps[(size_t)c * N + j];
        float mn = fmaxf(m, mc);
        s = s * __expf(m - mn) + sc * __expf(mc - mn);
        m = mn;
    }
    v[j] = EPS_LOG_MU - EPS_F * (m + __logf(s));
}

// ---------------- convergence check ----------------
__global__ void done_update(const float* __restrict__ blockDiff, int* done) {
    if (*done) return;
    int lane = threadIdx.x;
    float sum = (lane < 32) ? blockDiff[lane] : 0.0f;
#pragma unroll
    for (int off = 32; off; off >>= 1) sum += __shfl_xor(sum, off);
    if (lane == 0 && (sum * (1.0f / (float)N) < THRESH)) *done = 1;
}

// ---------------- final: sum(exp((u+v-c)/eps) * c), fused on-the-fly ----------------
__global__ __launch_bounds__(256) void plan_pass(const float* __restrict__ RP,
                                                 const float* __restrict__ CP,
                                                 const float* __restrict__ sq_r,
                                                 const float* __restrict__ sq_c,
                                                 const float* __restrict__ u,
                                                 const float* __restrict__ v,
                                                 float* __restrict__ part) {
    __shared__ float sA[64 * 64];
    __shared__ float sB[64 * 64];
    int rt = blockIdx.x & 127;
    int ck = blockIdx.x >> 7;
    int t  = threadIdx.x;
    int tx = t & 15, ty = t >> 4;
    int r0 = ty * 4, c0 = tx * 4;

    {
        int r  = t >> 2;
        int k0 = (t & 3) * 16;
        const float4* src = reinterpret_cast<const float4*>(RP + (size_t)(rt * 64 + r) * KDIM + k0);
        float4 a0 = src[0], a1 = src[1], a2 = src[2], a3 = src[3];
        float vals[16] = {a0.x,a0.y,a0.z,a0.w, a1.x,a1.y,a1.z,a1.w,
                          a2.x,a2.y,a2.z,a2.w, a3.x,a3.y,a3.z,a3.w};
#pragma unroll
        for (int q = 0; q < 16; ++q) sA[(k0 + q) * 64 + r] = vals[q];
    }

    float sqr[4], ui[4];
#pragma unroll
    for (int i = 0; i < 4; ++i) {
        sqr[i] = sq_r[rt * 64 + r0 + i];
        ui[i]  = u[rt * 64 + r0 + i];
    }

    float lsum = 0.0f;
    for (int jt = 0; jt < 2; ++jt) {
        int jbase = ck * 128 + jt * 64;
        __syncthreads();
        {
            int r  = t >> 2;
            int k0 = (t & 3) * 16;
            const float4* src = reinterpret_cast<const float4*>(CP + (size_t)(jbase + r) * KDIM + k0);
            float4 a0 = src[0], a1 = src[1], a2 = src[2], a3 = src[3];
            float vals[16] = {a0.x,a0.y,a0.z,a0.w, a1.x,a1.y,a1.z,a1.w,
                              a2.x,a2.y,a2.z,a2.w, a3.x,a3.y,a3.z,a3.w};
#pragma unroll
            for (int q = 0; q < 16; ++q) sB[(k0 + q) * 64 + r] = vals[q];
        }
        __syncthreads();

        float acc[4][4];
#pragma unroll
        for (int i = 0; i < 4; ++i)
#pragma unroll
            for (int j = 0; j < 4; ++j) acc[i][j] = 0.0f;

#pragma unroll 8
        for (int k = 0; k < 64; ++k) {
            float4 a4 = *reinterpret_cast<const float4*>(&sA[k * 64 + r0]);
            float4 b4 = *reinterpret_cast<const float4*>(&sB[k * 64 + c0]);
            float ar[4] = {a4.x, a4.y, a4.z, a4.w};
            float br[4] = {b4.x, b4.y, b4.z, b4.w};
#pragma unroll
            for (int i = 0; i < 4; ++i)
#pragma unroll
                for (int j = 0; j < 4; ++j)
                    acc[i][j] = fmaf(ar[i], br[j], acc[i][j]);
        }

        float4 v4  = *reinterpret_cast<const float4*>(v + jbase + c0);
        float4 sc4 = *reinterpret_cast<const float4*>(sq_c + jbase + c0);
        float vj[4]  = {v4.x, v4.y, v4.z, v4.w};
        float sqc[4] = {sc4.x, sc4.y, sc4.z, sc4.w};
#pragma unroll
        for (int i = 0; i < 4; ++i)
#pragma unroll
            for (int j = 0; j < 4; ++j) {
                float cst = fmaxf(sqr[i] + sqc[j] - 2.0f * acc[i][j], 0.0f);
                lsum += __expf((ui[i] + vj[j] - cst) * INV_EPS) * cst;
            }
    }

#pragma unroll
    for (int off = 32; off; off >>= 1) lsum += __shfl_xor(lsum, off);
    __shared__ float wsum[4];
    int lane = threadIdx.x & 63, wave = threadIdx.x >> 6;
    if (lane == 0) wsum[wave] = lsum;
    __syncthreads();
    if (threadIdx.x == 0)
        part[blockIdx.x] = wsum[0] + wsum[1] + wsum[2] + wsum[3];
}

__global__ void final_reduce(const float* __restrict__ part, float* __restrict__ out) {
    int t = threadIdx.x;
    float sum = 0.0f;
    for (int i = t; i < N; i += 256) sum += part[i];
#pragma unroll
    for (int off = 32; off; off >>= 1) sum += __shfl_xor(sum, off);
    __shared__ float wsum[4];
    int lane = t & 63, wave = t >> 6;
    if (lane == 0) wsum[wave] = sum;
    __syncthreads();
    if (t == 0) out[0] = wsum[0] + wsum[1] + wsum[2] + wsum[3];
}

extern "C" void kernel_launch(void* const* d_in, const int* in_sizes, int n_in,
                              void* d_out, int out_size, void* d_ws, size_t ws_size,
                              hipStream_t stream) {
    const float* S = (const float*)d_in[0];
    const float* T = (const float*)d_in[1];
    float* out = (float*)d_out;

    // workspace layout (~4.4 MB total, no 268 MB cost matrix)
    float* w = (float*)d_ws;
    size_t off = 0;
    float* sq_s      = w + off; off += N;
    float* sq_t      = w + off; off += N;
    float* u         = w + off; off += N;
    float* v         = w + off; off += N;
    float* pm        = w + off; off += (size_t)NCHUNK * N;
    float* ps        = w + off; off += (size_t)NCHUNK * N;
    float* blockDiff = w + off; off += 64;
    float* part      = w + off; off += N;
    int*   done      = (int*)(w + off);

    hipLaunchKernelGGL(init_kernel,  dim3(32), dim3(256), 0, stream, u, v, done);
    hipLaunchKernelGGL(norms_kernel, dim3(64), dim3(256), 0, stream, S, T, sq_s, sq_t);

    for (int it = 0; it < 50; ++it) {
        // row pass: u
        hipLaunchKernelGGL(lse_pass, dim3(8192), dim3(256), 0, stream,
                           S, T, sq_s, sq_t, v, pm, ps, done);
        hipLaunchKernelGGL(u_reduce, dim3(32), dim3(256), 0, stream, pm, ps, u, blockDiff, done);
        // col pass: v (roles swapped)
        hipLaunchKernelGGL(lse_pass, dim3(8192), dim3(256), 0, stream,
                           T, S, sq_t, sq_s, u, pm, ps, done);
        hipLaunchKernelGGL(v_reduce, dim3(32), dim3(256), 0, stream, pm, ps, v, done);
        hipLaunchKernelGGL(done_update, dim3(1), dim3(64), 0, stream, blockDiff, done);
    }

    hipLaunchKernelGGL(plan_pass, dim3(8192), dim3(256), 0, stream,
                       S, T, sq_s, sq_t, u, v, part);
    hipLaunchKernelGGL(final_reduce, dim3(1), dim3(256), 0, stream, part, out);
}

// Round 3
// 6975.558 us; speedup vs baseline: 2.2597x; 2.2597x over previous
//
#include <hip/hip_runtime.h>
#include <math.h>

#define N      8192
#define KDIM   64
#define EPS_F      0.05f
#define INV_EPS    20.0f
// eps * log(1/8192) ; log_mu == log_nu
#define EPS_LOG_MU (-0.45054566736396444f)
#define THRESH     0.001f
#define NEG_BIG    (-1e30f)
#define NCHUNK  16           // col chunks of 512
#define COLSPAN 512
#define ROWS_PER_BLOCK 128   // 4 waves x 32 rows

typedef __attribute__((ext_vector_type(8))) short bf16x8;
typedef __attribute__((ext_vector_type(4))) float f32x4;

static __device__ __forceinline__ unsigned short f2bf(float f) {
    unsigned u = __float_as_uint(f);
    u += 0x7FFFu + ((u >> 16) & 1u);
    return (unsigned short)(u >> 16);
}
static __device__ __forceinline__ float bf2f(unsigned short h) {
    return __uint_as_float(((unsigned)h) << 16);
}

// ---------------- init ----------------
__global__ void init_kernel(float* u, float* v, int* done) {
    int t = blockIdx.x * blockDim.x + threadIdx.x;
    if (t < N) { u[t] = 0.0f; v[t] = 0.0f; }
    if (t == 0) *done = 0;
}

// ---------------- squared row norms (fp32 exact) ----------------
__global__ void norms_kernel(const float* __restrict__ S, const float* __restrict__ T,
                             float* __restrict__ sq_s, float* __restrict__ sq_t) {
    int t = blockIdx.x * blockDim.x + threadIdx.x;   // 0 .. 16383
    const float* p = (t < N) ? S : T;
    int r = t & (N - 1);
    const float4* row = reinterpret_cast<const float4*>(p + (size_t)r * KDIM);
    float acc = 0.0f;
#pragma unroll
    for (int q = 0; q < KDIM / 4; ++q) {
        float4 a = row[q];
        acc += a.x * a.x + a.y * a.y + a.z * a.z + a.w * a.w;
    }
    if (t < N) sq_s[r] = acc; else sq_t[r] = acc;
}

// ---------------- split fp32 -> bf16 hi + lo ----------------
__global__ void split_kernel(const float* __restrict__ S, const float* __restrict__ T,
                             unsigned short* __restrict__ Shi, unsigned short* __restrict__ Slo,
                             unsigned short* __restrict__ Thi, unsigned short* __restrict__ Tlo) {
    int t = blockIdx.x * 256 + threadIdx.x;      // 0 .. 262143 (float4 units, both inputs)
    const int half = (N * KDIM) / 4;             // 131072
    const float* src = (t < half) ? S : T;
    unsigned short* dhi = (t < half) ? Shi : Thi;
    unsigned short* dlo = (t < half) ? Slo : Tlo;
    int e = (t < half) ? t : t - half;
    float4 x = reinterpret_cast<const float4*>(src)[e];
    unsigned short h0 = f2bf(x.x), h1 = f2bf(x.y), h2 = f2bf(x.z), h3 = f2bf(x.w);
    ushort4 hv = make_ushort4(h0, h1, h2, h3);
    ushort4 lv = make_ushort4(f2bf(x.x - bf2f(h0)), f2bf(x.y - bf2f(h1)),
                              f2bf(x.z - bf2f(h2)), f2bf(x.w - bf2f(h3)));
    reinterpret_cast<ushort4*>(dhi)[e] = hv;
    reinterpret_cast<ushort4*>(dlo)[e] = lv;
}

// ---------------- fused cost + LSE pass via split-bf16 MFMA ----------------
// For each row i of RP, online-lse over cols j in this block's 512-col chunk of
//   L_ij = (w_j - max(sq_r[i] + sq_c[j] - 2*dot(RP_i,CP_j), 0)) / eps
// Wave holds A-frags for 32 rows in registers; B-frags stream from L2.
// dot via 16x16x32 bf16 MFMA: Ah*Bh + Ah*Bl + Al*Bh (lo*lo dropped).
__global__ __launch_bounds__(256, 2) void lse_mfma(
        const unsigned short* __restrict__ RPhi, const unsigned short* __restrict__ RPlo,
        const unsigned short* __restrict__ CPhi, const unsigned short* __restrict__ CPlo,
        const float* __restrict__ sq_r, const float* __restrict__ sq_c,
        const float* __restrict__ w,
        float* __restrict__ pm, float* __restrict__ ps,
        const int* __restrict__ done) {
    if (*done) return;
    const int wave = threadIdx.x >> 6, lane = threadIdx.x & 63;
    const int lrow = lane & 15, kgrp = lane >> 4;
    const int rb = blockIdx.x / NCHUNK, ck = blockIdx.x % NCHUNK;
    const int rowbase = rb * ROWS_PER_BLOCK + wave * 32;
    const int colbase = ck * COLSPAN;

    // A fragments, held for the whole kernel. rt in {0,1} row tiles, ks in {0,1} k-steps.
    bf16x8 ahi[2][2], alo[2][2];
#pragma unroll
    for (int rt = 0; rt < 2; ++rt)
#pragma unroll
        for (int ks = 0; ks < 2; ++ks) {
            int aoff = (rowbase + rt * 16 + lrow) * KDIM + ks * 32 + kgrp * 8;
            ahi[rt][ks] = *reinterpret_cast<const bf16x8*>(RPhi + aoff);
            alo[rt][ks] = *reinterpret_cast<const bf16x8*>(RPlo + aoff);
        }

    // sq_r for my C-rows: row = rowbase + rt*16 + kgrp*4 + r
    float sqr[2][4];
#pragma unroll
    for (int rt = 0; rt < 2; ++rt) {
        float4 q = *reinterpret_cast<const float4*>(sq_r + rowbase + rt * 16 + kgrp * 4);
        sqr[rt][0] = q.x; sqr[rt][1] = q.y; sqr[rt][2] = q.z; sqr[rt][3] = q.w;
    }

    float m[2][4], s[2][4];
#pragma unroll
    for (int rt = 0; rt < 2; ++rt)
#pragma unroll
        for (int r = 0; r < 4; ++r) { m[rt][r] = NEG_BIG; s[rt][r] = 0.0f; }

    // software-pipelined B prefetch
    int col = colbase + lrow;
    bf16x8 nb_h0, nb_h1, nb_l0, nb_l1;
    {
        int boff = col * KDIM + kgrp * 8;
        nb_h0 = *reinterpret_cast<const bf16x8*>(CPhi + boff);
        nb_h1 = *reinterpret_cast<const bf16x8*>(CPhi + boff + 32);
        nb_l0 = *reinterpret_cast<const bf16x8*>(CPlo + boff);
        nb_l1 = *reinterpret_cast<const bf16x8*>(CPlo + boff + 32);
    }
    float nsqc = sq_c[col];
    float nw   = w[col];

    for (int ct = 0; ct < COLSPAN / 16; ++ct) {
        bf16x8 bh0 = nb_h0, bh1 = nb_h1, bl0 = nb_l0, bl1 = nb_l1;
        float sqc = nsqc;
        float w20 = nw * INV_EPS;
        if (ct < COLSPAN / 16 - 1) {
            col += 16;
            int boff = col * KDIM + kgrp * 8;
            nb_h0 = *reinterpret_cast<const bf16x8*>(CPhi + boff);
            nb_h1 = *reinterpret_cast<const bf16x8*>(CPhi + boff + 32);
            nb_l0 = *reinterpret_cast<const bf16x8*>(CPlo + boff);
            nb_l1 = *reinterpret_cast<const bf16x8*>(CPlo + boff + 32);
            nsqc = sq_c[col];
            nw   = w[col];
        }

        f32x4 acc0 = {0.0f, 0.0f, 0.0f, 0.0f};
        f32x4 acc1 = {0.0f, 0.0f, 0.0f, 0.0f};
        acc0 = __builtin_amdgcn_mfma_f32_16x16x32_bf16(ahi[0][0], bh0, acc0, 0, 0, 0);
        acc1 = __builtin_amdgcn_mfma_f32_16x16x32_bf16(ahi[1][0], bh0, acc1, 0, 0, 0);
        acc0 = __builtin_amdgcn_mfma_f32_16x16x32_bf16(ahi[0][1], bh1, acc0, 0, 0, 0);
        acc1 = __builtin_amdgcn_mfma_f32_16x16x32_bf16(ahi[1][1], bh1, acc1, 0, 0, 0);
        acc0 = __builtin_amdgcn_mfma_f32_16x16x32_bf16(ahi[0][0], bl0, acc0, 0, 0, 0);
        acc1 = __builtin_amdgcn_mfma_f32_16x16x32_bf16(ahi[1][0], bl0, acc1, 0, 0, 0);
        acc0 = __builtin_amdgcn_mfma_f32_16x16x32_bf16(ahi[0][1], bl1, acc0, 0, 0, 0);
        acc1 = __builtin_amdgcn_mfma_f32_16x16x32_bf16(ahi[1][1], bl1, acc1, 0, 0, 0);
        acc0 = __builtin_amdgcn_mfma_f32_16x16x32_bf16(alo[0][0], bh0, acc0, 0, 0, 0);
        acc1 = __builtin_amdgcn_mfma_f32_16x16x32_bf16(alo[1][0], bh0, acc1, 0, 0, 0);
        acc0 = __builtin_amdgcn_mfma_f32_16x16x32_bf16(alo[0][1], bh1, acc0, 0, 0, 0);
        acc1 = __builtin_amdgcn_mfma_f32_16x16x32_bf16(alo[1][1], bh1, acc1, 0, 0, 0);

        // epilogue: online-lse merge, one col per lane per row-slot
#pragma unroll
        for (int rt = 0; rt < 2; ++rt) {
#pragma unroll
            for (int r = 0; r < 4; ++r) {
                float d = (rt == 0) ? acc0[r] : acc1[r];
                float cost = fmaxf(fmaf(-2.0f, d, sqr[rt][r] + sqc), 0.0f);
                float L = fmaf(-INV_EPS, cost, w20);
                float mn = fmaxf(m[rt][r], L);
                s[rt][r] = fmaf(s[rt][r], __expf(m[rt][r] - mn), __expf(L - mn));
                m[rt][r] = mn;
            }
        }
    }

    // merge the 16 col-lanes (same kgrp, different lrow)
#pragma unroll
    for (int off = 1; off < 16; off <<= 1) {
#pragma unroll
        for (int rt = 0; rt < 2; ++rt)
#pragma unroll
            for (int r = 0; r < 4; ++r) {
                float mo = __shfl_xor(m[rt][r], off);
                float so = __shfl_xor(s[rt][r], off);
                float mn = fmaxf(m[rt][r], mo);
                s[rt][r] = s[rt][r] * __expf(m[rt][r] - mn) + so * __expf(mo - mn);
                m[rt][r] = mn;
            }
    }
    if (lrow == 0) {
#pragma unroll
        for (int rt = 0; rt < 2; ++rt)
#pragma unroll
            for (int r = 0; r < 4; ++r) {
                int row = rowbase + rt * 16 + kgrp * 4 + r;
                pm[(size_t)ck * N + row] = m[rt][r];
                ps[(size_t)ck * N + row] = s[rt][r];
            }
    }
}

// ---------------- u update (with convergence diff) ----------------
__global__ __launch_bounds__(256) void u_reduce(const float* __restrict__ pm,
                                                const float* __restrict__ ps,
                                                float* __restrict__ u,
                                                float* __restrict__ blockDiff,
                                                const int* __restrict__ done) {
    if (*done) return;
    int i = blockIdx.x * 256 + threadIdx.x;
    float m = NEG_BIG, s = 0.0f;
#pragma unroll
    for (int c = 0; c < NCHUNK; ++c) {
        float mc = pm[(size_t)c * N + i];
        float sc = ps[(size_t)c * N + i];
        float mn = fmaxf(m, mc);
        s = s * __expf(m - mn) + sc * __expf(mc - mn);
        m = mn;
    }
    float unew = EPS_LOG_MU - EPS_F * (m + __logf(s));
    float d = fabsf(unew - u[i]);
    u[i] = unew;
#pragma unroll
    for (int off = 32; off; off >>= 1) d += __shfl_xor(d, off);
    __shared__ float wsum[4];
    int lane = threadIdx.x & 63, wave = threadIdx.x >> 6;
    if (lane == 0) wsum[wave] = d;
    __syncthreads();
    if (threadIdx.x == 0)
        blockDiff[blockIdx.x] = wsum[0] + wsum[1] + wsum[2] + wsum[3];
}

// ---------------- v update ----------------
__global__ __launch_bounds__(256) void v_reduce(const float* __restrict__ pm,
                                                const float* __restrict__ ps,
                                                float* __restrict__ v,
                                                const int* __restrict__ done) {
    if (*done) return;
    int j = blockIdx.x * 256 + threadIdx.x;
    float m = NEG_BIG, s = 0.0f;
#pragma unroll
    for (int c = 0; c < NCHUNK; ++c) {
        float mc = pm[(size_t)c * N + j];
        float sc = ps[(size_t)c * N + j];
        float mn = fmaxf(m, mc);
        s = s * __expf(m - mn) + sc * __expf(mc - mn);
        m = mn;
    }
    v[j] = EPS_LOG_MU - EPS_F * (m + __logf(s));
}

// ---------------- convergence check ----------------
__global__ void done_update(const float* __restrict__ blockDiff, int* done) {
    if (*done) return;
    int lane = threadIdx.x;
    float sum = (lane < 32) ? blockDiff[lane] : 0.0f;
#pragma unroll
    for (int off = 32; off; off >>= 1) sum += __shfl_xor(sum, off);
    if (lane == 0 && (sum * (1.0f / (float)N) < THRESH)) *done = 1;
}

// ---------------- final: sum(exp((u+v-c)/eps) * c) via MFMA ----------------
__global__ __launch_bounds__(256, 2) void plan_mfma(
        const unsigned short* __restrict__ RPhi, const unsigned short* __restrict__ RPlo,
        const unsigned short* __restrict__ CPhi, const unsigned short* __restrict__ CPlo,
        const float* __restrict__ sq_r, const float* __restrict__ sq_c,
        const float* __restrict__ u, const float* __restrict__ v,
        float* __restrict__ part) {
    const int wave = threadIdx.x >> 6, lane = threadIdx.x & 63;
    const int lrow = lane & 15, kgrp = lane >> 4;
    const int rb = blockIdx.x / NCHUNK, ck = blockIdx.x % NCHUNK;
    const int rowbase = rb * ROWS_PER_BLOCK + wave * 32;
    const int colbase = ck * COLSPAN;

    bf16x8 ahi[2][2], alo[2][2];
#pragma unroll
    for (int rt = 0; rt < 2; ++rt)
#pragma unroll
        for (int ks = 0; ks < 2; ++ks) {
            int aoff = (rowbase + rt * 16 + lrow) * KDIM + ks * 32 + kgrp * 8;
            ahi[rt][ks] = *reinterpret_cast<const bf16x8*>(RPhi + aoff);
            alo[rt][ks] = *reinterpret_cast<const bf16x8*>(RPlo + aoff);
        }

    float sqr[2][4], ur[2][4];
#pragma unroll
    for (int rt = 0; rt < 2; ++rt) {
        float4 q = *reinterpret_cast<const float4*>(sq_r + rowbase + rt * 16 + kgrp * 4);
        sqr[rt][0] = q.x; sqr[rt][1] = q.y; sqr[rt][2] = q.z; sqr[rt][3] = q.w;
        float4 uu = *reinterpret_cast<const float4*>(u + rowbase + rt * 16 + kgrp * 4);
        ur[rt][0] = uu.x; ur[rt][1] = uu.y; ur[rt][2] = uu.z; ur[rt][3] = uu.w;
    }

    float lsum = 0.0f;
    int col = colbase + lrow;
    bf16x8 nb_h0, nb_h1, nb_l0, nb_l1;
    {
        int boff = col * KDIM + kgrp * 8;
        nb_h0 = *reinterpret_cast<const bf16x8*>(CPhi + boff);
        nb_h1 = *reinterpret_cast<const bf16x8*>(CPhi + boff + 32);
        nb_l0 = *reinterpret_cast<const bf16x8*>(CPlo + boff);
        nb_l1 = *reinterpret_cast<const bf16x8*>(CPlo + boff + 32);
    }
    float nvj = v[col];
    float nsqc = sq_c[col];

    for (int ct = 0; ct < COLSPAN / 16; ++ct) {
        bf16x8 bh0 = nb_h0, bh1 = nb_h1, bl0 = nb_l0, bl1 = nb_l1;
        float sqc = nsqc, vj = nvj;
        if (ct < COLSPAN / 16 - 1) {
            col += 16;
            int boff = col * KDIM + kgrp * 8;
            nb_h0 = *reinterpret_cast<const bf16x8*>(CPhi + boff);
            nb_h1 = *reinterpret_cast<const bf16x8*>(CPhi + boff + 32);
            nb_l0 = *reinterpret_cast<const bf16x8*>(CPlo + boff);
            nb_l1 = *reinterpret_cast<const bf16x8*>(CPlo + boff + 32);
            nvj = v[col];
            nsqc = sq_c[col];
        }

        f32x4 acc0 = {0.0f, 0.0f, 0.0f, 0.0f};
        f32x4 acc1 = {0.0f, 0.0f, 0.0f, 0.0f};
        acc0 = __builtin_amdgcn_mfma_f32_16x16x32_bf16(ahi[0][0], bh0, acc0, 0, 0, 0);
        acc1 = __builtin_amdgcn_mfma_f32_16x16x32_bf16(ahi[1][0], bh0, acc1, 0, 0, 0);
        acc0 = __builtin_amdgcn_mfma_f32_16x16x32_bf16(ahi[0][1], bh1, acc0, 0, 0, 0);
        acc1 = __builtin_amdgcn_mfma_f32_16x16x32_bf16(ahi[1][1], bh1, acc1, 0, 0, 0);
        acc0 = __builtin_amdgcn_mfma_f32_16x16x32_bf16(ahi[0][0], bl0, acc0, 0, 0, 0);
        acc1 = __builtin_amdgcn_mfma_f32_16x16x32_bf16(ahi[1][0], bl0, acc1, 0, 0, 0);
        acc0 = __builtin_amdgcn_mfma_f32_16x16x32_bf16(ahi[0][1], bl1, acc0, 0, 0, 0);
        acc1 = __builtin_amdgcn_mfma_f32_16x16x32_bf16(ahi[1][1], bl1, acc1, 0, 0, 0);
        acc0 = __builtin_amdgcn_mfma_f32_16x16x32_bf16(alo[0][0], bh0, acc0, 0, 0, 0);
        acc1 = __builtin_amdgcn_mfma_f32_16x16x32_bf16(alo[1][0], bh0, acc1, 0, 0, 0);
        acc0 = __builtin_amdgcn_mfma_f32_16x16x32_bf16(alo[0][1], bh1, acc0, 0, 0, 0);
        acc1 = __builtin_amdgcn_mfma_f32_16x16x32_bf16(alo[1][1], bh1, acc1, 0, 0, 0);

#pragma unroll
        for (int rt = 0; rt < 2; ++rt) {
#pragma unroll
            for (int r = 0; r < 4; ++r) {
                float d = (rt == 0) ? acc0[r] : acc1[r];
                float cost = fmaxf(fmaf(-2.0f, d, sqr[rt][r] + sqc), 0.0f);
                float arg = (ur[rt][r] + vj - cost) * INV_EPS;
                lsum = fmaf(__expf(arg), cost, lsum);
            }
        }
    }

#pragma unroll
    for (int off = 32; off; off >>= 1) lsum += __shfl_xor(lsum, off);
    __shared__ float wsum[4];
    if (lane == 0) wsum[wave] = lsum;
    __syncthreads();
    if (threadIdx.x == 0)
        part[blockIdx.x] = wsum[0] + wsum[1] + wsum[2] + wsum[3];
}

__global__ void final_reduce(const float* __restrict__ part, float* __restrict__ out) {
    int t = threadIdx.x;
    float sum = 0.0f;
    for (int i = t; i < 1024; i += 256) sum += part[i];
#pragma unroll
    for (int off = 32; off; off >>= 1) sum += __shfl_xor(sum, off);
    __shared__ float wsum[4];
    int lane = t & 63, wave = t >> 6;
    if (lane == 0) wsum[wave] = sum;
    __syncthreads();
    if (t == 0) out[0] = wsum[0] + wsum[1] + wsum[2] + wsum[3];
}

extern "C" void kernel_launch(void* const* d_in, const int* in_sizes, int n_in,
                              void* d_out, int out_size, void* d_ws, size_t ws_size,
                              hipStream_t stream) {
    const float* S = (const float*)d_in[0];
    const float* T = (const float*)d_in[1];
    float* out = (float*)d_out;

    // workspace (~5.3 MB): bf16 hi/lo arrays first (16B-aligned), then fp32 state
    unsigned short* us = (unsigned short*)d_ws;
    unsigned short* Shi = us;                 // N*KDIM each
    unsigned short* Slo = us + (size_t)N * KDIM;
    unsigned short* Thi = us + (size_t)2 * N * KDIM;
    unsigned short* Tlo = us + (size_t)3 * N * KDIM;
    float* w = (float*)(us + (size_t)4 * N * KDIM);
    size_t off = 0;
    float* sq_s      = w + off; off += N;
    float* sq_t      = w + off; off += N;
    float* u         = w + off; off += N;
    float* v         = w + off; off += N;
    float* pm        = w + off; off += (size_t)NCHUNK * N;
    float* ps        = w + off; off += (size_t)NCHUNK * N;
    float* blockDiff = w + off; off += 64;
    float* part      = w + off; off += 1024;
    int*   done      = (int*)(w + off);

    hipLaunchKernelGGL(init_kernel,  dim3(32),   dim3(256), 0, stream, u, v, done);
    hipLaunchKernelGGL(norms_kernel, dim3(64),   dim3(256), 0, stream, S, T, sq_s, sq_t);
    hipLaunchKernelGGL(split_kernel, dim3(1024), dim3(256), 0, stream, S, T, Shi, Slo, Thi, Tlo);

    const int LSE_BLOCKS = (N / ROWS_PER_BLOCK) * NCHUNK;   // 1024
    for (int it = 0; it < 50; ++it) {
        // row pass: u  (RP = S, CP = T, w = v)
        hipLaunchKernelGGL(lse_mfma, dim3(LSE_BLOCKS), dim3(256), 0, stream,
                           Shi, Slo, Thi, Tlo, sq_s, sq_t, v, pm, ps, done);
        hipLaunchKernelGGL(u_reduce, dim3(32), dim3(256), 0, stream, pm, ps, u, blockDiff, done);
        // col pass: v  (RP = T, CP = S, w = u)
        hipLaunchKernelGGL(lse_mfma, dim3(LSE_BLOCKS), dim3(256), 0, stream,
                           Thi, Tlo, Shi, Slo, sq_t, sq_s, u, pm, ps, done);
        hipLaunchKernelGGL(v_reduce, dim3(32), dim3(256), 0, stream, pm, ps, v, done);
        hipLaunchKernelGGL(done_update, dim3(1), dim3(64), 0, stream, blockDiff, done);
    }

    hipLaunchKernelGGL(plan_mfma, dim3(LSE_BLOCKS), dim3(256), 0, stream,
                       Shi, Slo, Thi, Tlo, sq_s, sq_t, u, v, part);
    hipLaunchKernelGGL(final_reduce, dim3(1), dim3(256), 0, stream, part, out);
}

// Round 5
// 4580.133 us; speedup vs baseline: 3.4415x; 1.5230x over previous
//
#include <hip/hip_runtime.h>

#define N      8192
#define KDIM   64
#define EPS_F      0.05f
#define INV_EPS    20.0f
// base-2 scaled constants
#define SCALE2    28.853900817779268f    // 20 / ln2
#define TWOSCALE  57.707801635558536f    // 40 / ln2
#define EPSLN2    0.034657359027997264f  // 0.05 * ln2
#define EPS_LOG_MU (-0.45054566736396444f)
#define THRESH     0.001f
#define NEG_BIG    (-1e30f)
#define NCHUNK  32           // col chunks of 256
#define COLSPAN 256
#define ROWS_PER_BLOCK 256   // 4 waves x 64 rows

typedef __attribute__((ext_vector_type(8))) short bf16x8;
typedef __attribute__((ext_vector_type(4))) float f32x4;

// v_exp_f32 / v_log_f32 are base-2 on gfx950
static __device__ __forceinline__ float exp2fast(float x) { return __builtin_amdgcn_exp2f(x); }
static __device__ __forceinline__ float log2fast(float x) { return __builtin_amdgcn_logf(x); }

static __device__ __forceinline__ unsigned short f2bf(float f) {
    unsigned u = __float_as_uint(f);
    u += 0x7FFFu + ((u >> 16) & 1u);
    return (unsigned short)(u >> 16);
}
static __device__ __forceinline__ float bf2f(unsigned short h) {
    return __uint_as_float(((unsigned)h) << 16);
}

// ---------------- squared row norms (fp32 exact) ----------------
__global__ void norms_kernel(const float* __restrict__ S, const float* __restrict__ T,
                             float* __restrict__ sq_s, float* __restrict__ sq_t,
                             float* __restrict__ sq_s2, float* __restrict__ sq_t2) {
    int t = blockIdx.x * blockDim.x + threadIdx.x;   // 0 .. 16383
    const float* p = (t < N) ? S : T;
    int r = t & (N - 1);
    const float4* row = reinterpret_cast<const float4*>(p + (size_t)r * KDIM);
    float acc = 0.0f;
#pragma unroll
    for (int q = 0; q < KDIM / 4; ++q) {
        float4 a = row[q];
        acc += a.x * a.x + a.y * a.y + a.z * a.z + a.w * a.w;
    }
    if (t < N) { sq_s[r] = acc; sq_s2[r] = acc * SCALE2; }
    else       { sq_t[r] = acc; sq_t2[r] = acc * SCALE2; }
}

// ---------------- init (after norms: needs sq_t2) ----------------
__global__ void init_kernel(float* u, float* v, float* alphaT,
                            const float* __restrict__ sq_t2, int* done) {
    int t = blockIdx.x * blockDim.x + threadIdx.x;
    if (t < N) { u[t] = 0.0f; v[t] = 0.0f; alphaT[t] = -sq_t2[t]; }
    if (t == 0) *done = 0;
}

// ---------------- split fp32 -> bf16 hi + lo ----------------
__global__ void split_kernel(const float* __restrict__ S, const float* __restrict__ T,
                             unsigned short* __restrict__ Shi, unsigned short* __restrict__ Slo,
                             unsigned short* __restrict__ Thi, unsigned short* __restrict__ Tlo) {
    int t = blockIdx.x * 256 + threadIdx.x;      // float4 units, both inputs
    const int half = (N * KDIM) / 4;             // 131072
    const float* src = (t < half) ? S : T;
    unsigned short* dhi = (t < half) ? Shi : Thi;
    unsigned short* dlo = (t < half) ? Slo : Tlo;
    int e = (t < half) ? t : t - half;
    float4 x = reinterpret_cast<const float4*>(src)[e];
    unsigned short h0 = f2bf(x.x), h1 = f2bf(x.y), h2 = f2bf(x.z), h3 = f2bf(x.w);
    ushort4 hv = make_ushort4(h0, h1, h2, h3);
    ushort4 lv = make_ushort4(f2bf(x.x - bf2f(h0)), f2bf(x.y - bf2f(h1)),
                              f2bf(x.z - bf2f(h2)), f2bf(x.w - bf2f(h3)));
    reinterpret_cast<ushort4*>(dhi)[e] = hv;
    reinterpret_cast<ushort4*>(dlo)[e] = lv;
}

// ---------------- fused cost + LSE pass (base-2, batched online-lse) ----------------
// Wave holds RP fragments for 64 rows (B operand); streams CP cols (A operand).
// L'_ij = alpha[j] + TWOSCALE*dot_ij  (row-constant -sqr2[i] applied at the write).
// D layout: i = lane&15 (per it-group), j = jbase + kgrp*4 + r.
__global__ __launch_bounds__(256, 3) void lse_mfma(
        const unsigned short* __restrict__ CPhi, const unsigned short* __restrict__ CPlo,
        const unsigned short* __restrict__ RPhi, const unsigned short* __restrict__ RPlo,
        const float* __restrict__ alpha,   // w_j*SCALE2 - sqc2[j]
        const float* __restrict__ sqr2,    // ||r_i||^2 * SCALE2
        float* __restrict__ pm, float* __restrict__ ps,
        const int* __restrict__ done) {
    if (*done) return;
    const int wave = threadIdx.x >> 6, lane = threadIdx.x & 63;
    const int lrow = lane & 15, kgrp = lane >> 4;
    const int rb = blockIdx.x >> 5, ck = blockIdx.x & 31;
    const int rowbase = rb * ROWS_PER_BLOCK + wave * 64;
    const int jbase0 = ck * COLSPAN;

    // held RP fragments: 4 row-tiles x 2 k-steps, hi+lo (64 VGPR)
    bf16x8 bh[4][2], bl[4][2];
#pragma unroll
    for (int it = 0; it < 4; ++it)
#pragma unroll
        for (int ks = 0; ks < 2; ++ks) {
            int boff = (rowbase + it * 16 + lrow) * KDIM + ks * 32 + kgrp * 8;
            bh[it][ks] = *reinterpret_cast<const bf16x8*>(RPhi + boff);
            bl[it][ks] = *reinterpret_cast<const bf16x8*>(RPlo + boff);
        }

    float m[4], s[4];
#pragma unroll
    for (int it = 0; it < 4; ++it) { m[it] = NEG_BIG; s[it] = 0.0f; }

    // prefetch ct = 0
    int jb = jbase0;
    bf16x8 nah0, nah1, nal0, nal1;
    float4 nav;
    {
        int aoff = (jb + lrow) * KDIM + kgrp * 8;
        nah0 = *reinterpret_cast<const bf16x8*>(CPhi + aoff);
        nah1 = *reinterpret_cast<const bf16x8*>(CPhi + aoff + 32);
        nal0 = *reinterpret_cast<const bf16x8*>(CPlo + aoff);
        nal1 = *reinterpret_cast<const bf16x8*>(CPlo + aoff + 32);
        nav  = *reinterpret_cast<const float4*>(alpha + jb + kgrp * 4);
    }

    for (int ct = 0; ct < COLSPAN / 16; ++ct) {
        bf16x8 ah0 = nah0, ah1 = nah1, al0 = nal0, al1 = nal1;
        float4 av = nav;
        if (ct < COLSPAN / 16 - 1) {
            jb += 16;
            int aoff = (jb + lrow) * KDIM + kgrp * 8;
            nah0 = *reinterpret_cast<const bf16x8*>(CPhi + aoff);
            nah1 = *reinterpret_cast<const bf16x8*>(CPhi + aoff + 32);
            nal0 = *reinterpret_cast<const bf16x8*>(CPlo + aoff);
            nal1 = *reinterpret_cast<const bf16x8*>(CPlo + aoff + 32);
            nav  = *reinterpret_cast<const float4*>(alpha + jb + kgrp * 4);
        }

        f32x4 acc[4];
#pragma unroll
        for (int it = 0; it < 4; ++it) {
            f32x4 a = {0.0f, 0.0f, 0.0f, 0.0f};
            a = __builtin_amdgcn_mfma_f32_16x16x32_bf16(ah0, bh[it][0], a, 0, 0, 0);
            a = __builtin_amdgcn_mfma_f32_16x16x32_bf16(ah1, bh[it][1], a, 0, 0, 0);
            a = __builtin_amdgcn_mfma_f32_16x16x32_bf16(ah0, bl[it][0], a, 0, 0, 0);
            a = __builtin_amdgcn_mfma_f32_16x16x32_bf16(ah1, bl[it][1], a, 0, 0, 0);
            a = __builtin_amdgcn_mfma_f32_16x16x32_bf16(al0, bh[it][0], a, 0, 0, 0);
            a = __builtin_amdgcn_mfma_f32_16x16x32_bf16(al1, bh[it][1], a, 0, 0, 0);
            acc[it] = a;
        }

#pragma unroll
        for (int it = 0; it < 4; ++it) {
            float L0 = fmaf(TWOSCALE, acc[it][0], av.x);
            float L1 = fmaf(TWOSCALE, acc[it][1], av.y);
            float L2 = fmaf(TWOSCALE, acc[it][2], av.z);
            float L3 = fmaf(TWOSCALE, acc[it][3], av.w);
            float mx = fmaxf(fmaxf(L0, L1), fmaxf(L2, L3));
            float mn = fmaxf(m[it], mx);
            float rs = exp2fast(m[it] - mn);
            float e  = (exp2fast(L0 - mn) + exp2fast(L1 - mn)) +
                       (exp2fast(L2 - mn) + exp2fast(L3 - mn));
            s[it] = fmaf(s[it], rs, e);
            m[it] = mn;
        }
    }

    // merge across the 4 kgrp groups (they share the same 16 rows)
#pragma unroll
    for (int off = 16; off < 64; off <<= 1) {
#pragma unroll
        for (int it = 0; it < 4; ++it) {
            float mo = __shfl_xor(m[it], off);
            float so = __shfl_xor(s[it], off);
            float mn = fmaxf(m[it], mo);
            s[it] = s[it] * exp2fast(m[it] - mn) + so * exp2fast(mo - mn);
            m[it] = mn;
        }
    }
    if (kgrp == 0) {
#pragma unroll
        for (int it = 0; it < 4; ++it) {
            int row = rowbase + it * 16 + lrow;
            pm[(size_t)ck * N + row] = m[it] - sqr2[row];
            ps[(size_t)ck * N + row] = s[it];
        }
    }
}

// ---------------- u update (+ alphaS for the following col pass) ----------------
__global__ __launch_bounds__(256) void u_reduce(const float* __restrict__ pm,
                                                const float* __restrict__ ps,
                                                float* __restrict__ u,
                                                float* __restrict__ alphaS,
                                                const float* __restrict__ sqs2,
                                                float* __restrict__ blockDiff,
                                                const int* __restrict__ done) {
    if (*done) return;
    int i = blockIdx.x * 256 + threadIdx.x;
    float m = NEG_BIG, s = 0.0f;
#pragma unroll
    for (int c = 0; c < NCHUNK; ++c) {
        float mc = pm[(size_t)c * N + i];
        float sc = ps[(size_t)c * N + i];
        float mn = fmaxf(m, mc);
        s = s * exp2fast(m - mn) + sc * exp2fast(mc - mn);
        m = mn;
    }
    float lse2 = m + log2fast(s);
    float unew = EPS_LOG_MU - EPSLN2 * lse2;
    float d = fabsf(unew - u[i]);
    u[i] = unew;
    alphaS[i] = fmaf(unew, SCALE2, -sqs2[i]);
#pragma unroll
    for (int off = 32; off; off >>= 1) d += __shfl_xor(d, off);
    __shared__ float wsum[4];
    int lane = threadIdx.x & 63, wave = threadIdx.x >> 6;
    if (lane == 0) wsum[wave] = d;
    __syncthreads();
    if (threadIdx.x == 0)
        blockDiff[blockIdx.x] = wsum[0] + wsum[1] + wsum[2] + wsum[3];
}

// ---------------- v update (+ alphaT for the next row pass) ----------------
__global__ __launch_bounds__(256) void v_reduce(const float* __restrict__ pm,
                                                const float* __restrict__ ps,
                                                float* __restrict__ v,
                                                float* __restrict__ alphaT,
                                                const float* __restrict__ sqt2,
                                                const int* __restrict__ done) {
    if (*done) return;
    int j = blockIdx.x * 256 + threadIdx.x;
    float m = NEG_BIG, s = 0.0f;
#pragma unroll
    for (int c = 0; c < NCHUNK; ++c) {
        float mc = pm[(size_t)c * N + j];
        float sc = ps[(size_t)c * N + j];
        float mn = fmaxf(m, mc);
        s = s * exp2fast(m - mn) + sc * exp2fast(mc - mn);
        m = mn;
    }
    float vnew = EPS_LOG_MU - EPSLN2 * (m + log2fast(s));
    v[j] = vnew;
    alphaT[j] = fmaf(vnew, SCALE2, -sqt2[j]);
}

// ---------------- convergence check ----------------
__global__ void done_update(const float* __restrict__ blockDiff, int* done) {
    if (*done) return;
    int lane = threadIdx.x;
    float sum = (lane < 32) ? blockDiff[lane] : 0.0f;
#pragma unroll
    for (int off = 32; off; off >>= 1) sum += __shfl_xor(sum, off);
    if (lane == 0 && (sum * (1.0f / (float)N) < THRESH)) *done = 1;
}

// ---------------- final: sum(exp((u+v-c)/eps) * c) via MFMA (round-3 layout) ----------------
__global__ __launch_bounds__(256, 2) void plan_mfma(
        const unsigned short* __restrict__ RPhi, const unsigned short* __restrict__ RPlo,
        const unsigned short* __restrict__ CPhi, const unsigned short* __restrict__ CPlo,
        const float* __restrict__ sq_r, const float* __restrict__ sq_c,
        const float* __restrict__ u, const float* __restrict__ v,
        float* __restrict__ part) {
    const int wave = threadIdx.x >> 6, lane = threadIdx.x & 63;
    const int lrow = lane & 15, kgrp = lane >> 4;
    const int rb = blockIdx.x / 16, ck = blockIdx.x % 16;
    const int rowbase = rb * 128 + wave * 32;
    const int colbase = ck * 512;

    bf16x8 ahi[2][2], alo[2][2];
#pragma unroll
    for (int rt = 0; rt < 2; ++rt)
#pragma unroll
        for (int ks = 0; ks < 2; ++ks) {
            int aoff = (rowbase + rt * 16 + lrow) * KDIM + ks * 32 + kgrp * 8;
            ahi[rt][ks] = *reinterpret_cast<const bf16x8*>(RPhi + aoff);
            alo[rt][ks] = *reinterpret_cast<const bf16x8*>(RPlo + aoff);
        }

    float sqr[2][4], ur[2][4];
#pragma unroll
    for (int rt = 0; rt < 2; ++rt) {
        float4 q = *reinterpret_cast<const float4*>(sq_r + rowbase + rt * 16 + kgrp * 4);
        sqr[rt][0] = q.x; sqr[rt][1] = q.y; sqr[rt][2] = q.z; sqr[rt][3] = q.w;
        float4 uu = *reinterpret_cast<const float4*>(u + rowbase + rt * 16 + kgrp * 4);
        ur[rt][0] = uu.x; ur[rt][1] = uu.y; ur[rt][2] = uu.z; ur[rt][3] = uu.w;
    }

    float lsum = 0.0f;
    int col = colbase + lrow;
    bf16x8 nb_h0, nb_h1, nb_l0, nb_l1;
    {
        int boff = col * KDIM + kgrp * 8;
        nb_h0 = *reinterpret_cast<const bf16x8*>(CPhi + boff);
        nb_h1 = *reinterpret_cast<const bf16x8*>(CPhi + boff + 32);
        nb_l0 = *reinterpret_cast<const bf16x8*>(CPlo + boff);
        nb_l1 = *reinterpret_cast<const bf16x8*>(CPlo + boff + 32);
    }
    float nvj = v[col];
    float nsqc = sq_c[col];

    for (int ct = 0; ct < 32; ++ct) {
        bf16x8 bh0 = nb_h0, bh1 = nb_h1, bl0 = nb_l0, bl1 = nb_l1;
        float sqc = nsqc, vj = nvj;
        if (ct < 31) {
            col += 16;
            int boff = col * KDIM + kgrp * 8;
            nb_h0 = *reinterpret_cast<const bf16x8*>(CPhi + boff);
            nb_h1 = *reinterpret_cast<const bf16x8*>(CPhi + boff + 32);
            nb_l0 = *reinterpret_cast<const bf16x8*>(CPlo + boff);
            nb_l1 = *reinterpret_cast<const bf16x8*>(CPlo + boff + 32);
            nvj = v[col];
            nsqc = sq_c[col];
        }

        f32x4 acc0 = {0.0f, 0.0f, 0.0f, 0.0f};
        f32x4 acc1 = {0.0f, 0.0f, 0.0f, 0.0f};
        acc0 = __builtin_amdgcn_mfma_f32_16x16x32_bf16(ahi[0][0], bh0, acc0, 0, 0, 0);
        acc1 = __builtin_amdgcn_mfma_f32_16x16x32_bf16(ahi[1][0], bh0, acc1, 0, 0, 0);
        acc0 = __builtin_amdgcn_mfma_f32_16x16x32_bf16(ahi[0][1], bh1, acc0, 0, 0, 0);
        acc1 = __builtin_amdgcn_mfma_f32_16x16x32_bf16(ahi[1][1], bh1, acc1, 0, 0, 0);
        acc0 = __builtin_amdgcn_mfma_f32_16x16x32_bf16(ahi[0][0], bl0, acc0, 0, 0, 0);
        acc1 = __builtin_amdgcn_mfma_f32_16x16x32_bf16(ahi[1][0], bl0, acc1, 0, 0, 0);
        acc0 = __builtin_amdgcn_mfma_f32_16x16x32_bf16(ahi[0][1], bl1, acc0, 0, 0, 0);
        acc1 = __builtin_amdgcn_mfma_f32_16x16x32_bf16(ahi[1][1], bl1, acc1, 0, 0, 0);
        acc0 = __builtin_amdgcn_mfma_f32_16x16x32_bf16(alo[0][0], bh0, acc0, 0, 0, 0);
        acc1 = __builtin_amdgcn_mfma_f32_16x16x32_bf16(alo[1][0], bh0, acc1, 0, 0, 0);
        acc0 = __builtin_amdgcn_mfma_f32_16x16x32_bf16(alo[0][1], bh1, acc0, 0, 0, 0);
        acc1 = __builtin_amdgcn_mfma_f32_16x16x32_bf16(alo[1][1], bh1, acc1, 0, 0, 0);

#pragma unroll
        for (int rt = 0; rt < 2; ++rt) {
#pragma unroll
            for (int r = 0; r < 4; ++r) {
                float d = (rt == 0) ? acc0[r] : acc1[r];
                float cost = fmaxf(fmaf(-2.0f, d, sqr[rt][r] + sqc), 0.0f);
                float arg = (ur[rt][r] + vj - cost) * SCALE2;   // base-2 exponent
                lsum = fmaf(exp2fast(arg), cost, lsum);
            }
        }
    }

#pragma unroll
    for (int off = 32; off; off >>= 1) lsum += __shfl_xor(lsum, off);
    __shared__ float wsum[4];
    if (lane == 0) wsum[wave] = lsum;
    __syncthreads();
    if (threadIdx.x == 0)
        part[blockIdx.x] = wsum[0] + wsum[1] + wsum[2] + wsum[3];
}

__global__ void final_reduce(const float* __restrict__ part, float* __restrict__ out) {
    int t = threadIdx.x;
    float sum = 0.0f;
    for (int i = t; i < 1024; i += 256) sum += part[i];
#pragma unroll
    for (int off = 32; off; off >>= 1) sum += __shfl_xor(sum, off);
    __shared__ float wsum[4];
    int lane = t & 63, wave = t >> 6;
    if (lane == 0) wsum[wave] = sum;
    __syncthreads();
    if (t == 0) out[0] = wsum[0] + wsum[1] + wsum[2] + wsum[3];
}

extern "C" void kernel_launch(void* const* d_in, const int* in_sizes, int n_in,
                              void* d_out, int out_size, void* d_ws, size_t ws_size,
                              hipStream_t stream) {
    const float* S = (const float*)d_in[0];
    const float* T = (const float*)d_in[1];
    float* out = (float*)d_out;

    // workspace (~6.4 MB)
    unsigned short* us = (unsigned short*)d_ws;
    unsigned short* Shi = us;
    unsigned short* Slo = us + (size_t)N * KDIM;
    unsigned short* Thi = us + (size_t)2 * N * KDIM;
    unsigned short* Tlo = us + (size_t)3 * N * KDIM;
    float* w = (float*)(us + (size_t)4 * N * KDIM);
    size_t off = 0;
    float* sq_s      = w + off; off += N;
    float* sq_t      = w + off; off += N;
    float* sq_s2     = w + off; off += N;
    float* sq_t2     = w + off; off += N;
    float* u         = w + off; off += N;
    float* v         = w + off; off += N;
    float* alphaS    = w + off; off += N;
    float* alphaT    = w + off; off += N;
    float* pm        = w + off; off += (size_t)NCHUNK * N;
    float* ps        = w + off; off += (size_t)NCHUNK * N;
    float* blockDiff = w + off; off += 64;
    float* part      = w + off; off += 1024;
    int*   done      = (int*)(w + off);

    hipLaunchKernelGGL(norms_kernel, dim3(64),   dim3(256), 0, stream,
                       S, T, sq_s, sq_t, sq_s2, sq_t2);
    hipLaunchKernelGGL(init_kernel,  dim3(32),   dim3(256), 0, stream, u, v, alphaT, sq_t2, done);
    hipLaunchKernelGGL(split_kernel, dim3(1024), dim3(256), 0, stream, S, T, Shi, Slo, Thi, Tlo);

    const int LSE_BLOCKS = (N / ROWS_PER_BLOCK) * NCHUNK;   // 32*32 = 1024
    for (int it = 0; it < 50; ++it) {
        // row pass: cols = T (A operand), rows = S (B held), w = v
        hipLaunchKernelGGL(lse_mfma, dim3(LSE_BLOCKS), dim3(256), 0, stream,
                           Thi, Tlo, Shi, Slo, alphaT, sq_s2, pm, ps, done);
        hipLaunchKernelGGL(u_reduce, dim3(32), dim3(256), 0, stream,
                           pm, ps, u, alphaS, sq_s2, blockDiff, done);
        // col pass: cols = S, rows = T, w = u
        hipLaunchKernelGGL(lse_mfma, dim3(LSE_BLOCKS), dim3(256), 0, stream,
                           Shi, Slo, Thi, Tlo, alphaS, sq_t2, pm, ps, done);
        hipLaunchKernelGGL(v_reduce, dim3(32), dim3(256), 0, stream,
                           pm, ps, v, alphaT, sq_t2, done);
        hipLaunchKernelGGL(done_update, dim3(1), dim3(64), 0, stream, blockDiff, done);
    }

    hipLaunchKernelGGL(plan_mfma, dim3(1024), dim3(256), 0, stream,
                       Shi, Slo, Thi, Tlo, sq_s, sq_t, u, v, part);
    hipLaunchKernelGGL(final_reduce, dim3(1), dim3(256), 0, stream, part, out);
}